// Round 3
// baseline (2554.504 us; speedup 1.0000x reference)
//
#include <hip/hip_runtime.h>
#include <cstdint>
#include <cstddef>

// Problem dims
#define NB    64      // batch
#define SENC  64      // encoder steps
#define TDEC  31      // decoder steps (tgt[:, :-1])
#define EDIM  256
#define HDIM  512
#define VOCAB 32000
#define MROWS (NB * TDEC)   // 1984
#define MPAD  2048
#define NBLK  256           // recurrence grid (cooperative)

// workspace byte offsets
#define OFF_HTA  0
#define OFF_HTB  (OFF_HTA + HDIM * NB * 4)
#define OFF_XPE  (OFF_HTB + HDIM * NB * 4)
#define OFF_XPD  (OFF_XPE + 256 * SENC * 8 * NB * 4)
#define OFF_HS   (OFF_XPD + 256 * TDEC * 8 * NB * 4)
#define OFF_FCW  (OFF_HS + MPAD * HDIM * 2)
// barrier flag array (NBLK u32 = 1 KB) overlays the first bytes of the hs PAD
// rows (rows MROWS..MPAD-1). Those rows only feed fc_gemm output rows
// m>=MROWS, which are discarded by the m<MROWS guard — garbage is harmless.

typedef __attribute__((ext_vector_type(8))) short bf16x8;   // 8 bf16 (4 VGPRs)
typedef __attribute__((ext_vector_type(4))) float f32x4;

__device__ __forceinline__ float sigf(float x) { return 1.0f / (1.0f + __expf(-x)); }
__device__ __forceinline__ float tanhfast(float x) {
  return 1.0f - 2.0f / (__expf(2.0f * x) + 1.0f);
}
__device__ __forceinline__ unsigned short f2bf(float x) {
  unsigned int u = __float_as_uint(x);
  u += 0x7fffu + ((u >> 16) & 1u);   // RNE
  return (unsigned short)(u >> 16);
}
__device__ __forceinline__ unsigned pack2(float a, float b) {
  return (unsigned)f2bf(a) | ((unsigned)f2bf(b) << 16);
}

// ---------------- setup: fcw bf16 convert + zeros ----------------
__global__ __launch_bounds__(256) void setup_k(const float* __restrict__ fc_W,
                                               unsigned short* __restrict__ fcw,
                                               float* __restrict__ hTA,
                                               unsigned short* __restrict__ hs,
                                               float* __restrict__ out) {
  const int gt = blockIdx.x * 256 + threadIdx.x;
  const int GSZ = 2048 * 256;
  const float4* s4 = (const float4*)fc_W;
  uint4* d4 = (uint4*)fcw;
  for (int i = gt; i < (VOCAB * HDIM / 8); i += GSZ) {
    float4 x = s4[2 * i], y = s4[2 * i + 1];
    uint4 v;
    v.x = pack2(x.x, x.y); v.y = pack2(x.z, x.w);
    v.z = pack2(y.x, y.y); v.w = pack2(y.z, y.w);
    d4[i] = v;
  }
  float4 z4 = make_float4(0.f, 0.f, 0.f, 0.f);
  // out[:,0,:] = 0
  for (int j = gt; j < NB * (VOCAB / 4); j += GSZ) {
    int b = j / (VOCAB / 4), q = j - b * (VOCAB / 4);
    ((float4*)out)[(size_t)b * (32 * (VOCAB / 4)) + q] = z4;
  }
  if (gt < HDIM * NB / 4) ((float4*)hTA)[gt] = z4;
  // hs pad rows (also zeroes the overlaid barrier flag array)
  if (gt < (MPAD - MROWS) * HDIM / 8) {
    uint4 uz = {0u, 0u, 0u, 0u};
    ((uint4*)(hs + (size_t)MROWS * HDIM))[gt] = uz;
  }
}

// ---------------- xp: input projections ----------------
// xp[s][r][b] = bias_r + sum_e Wih[row_g(r)][e] * emb[idx[b][s]][e]
__device__ void xp_phase(const int* idxmat, int istride, int S,
                         const float* emb, const float* Wih,
                         const float* bih, const float* bhh,
                         float* xp_out, int bid, int tid,
                         float* W_lds, float* pbuf, float* bias_lds) {
  const int lane = tid & 63;
  const int w = tid >> 6;
  {
    int r = tid >> 5;                  // 0..7
    int e0 = (tid & 31) * 8;           // 0..248
    int row_g = (r >> 1) * HDIM + bid * 2 + (r & 1);
    const float* sp = Wih + (size_t)row_g * EDIM + e0;
    *(float4*)&W_lds[r * EDIM + e0]     = *(const float4*)sp;
    *(float4*)&W_lds[r * EDIM + e0 + 4] = *(const float4*)(sp + 4);
    if (tid < 8) {
      int rg = (tid >> 1) * HDIM + bid * 2 + (tid & 1);
      bias_lds[tid] = bih[rg] + bhh[rg];
    }
  }
  __syncthreads();
  for (int s = 0; s < S; ++s) {
    int idx = idxmat[lane * istride + s];
    const float* xrow = emb + (size_t)idx * EDIM;
    float acc[8];
#pragma unroll
    for (int r = 0; r < 8; ++r) acc[r] = 0.0f;
    for (int e = w * 64; e < w * 64 + 64; e += 4) {
      float4 xv = *(const float4*)&xrow[e];
#pragma unroll
      for (int r = 0; r < 8; ++r) {
        float4 wv = *(const float4*)&W_lds[r * EDIM + e];
        acc[r] += wv.x * xv.x + wv.y * xv.y + wv.z * xv.z + wv.w * xv.w;
      }
    }
#pragma unroll
    for (int r = 0; r < 8; ++r) pbuf[(w * 8 + r) * 64 + lane] = acc[r];
    __syncthreads();
    if (tid < 128) {
      int unit = tid >> 6, b = tid & 63;
#pragma unroll
      for (int gate = 0; gate < 4; ++gate) {
        int r = gate * 2 + unit;
        float v = bias_lds[r];
#pragma unroll
        for (int ww = 0; ww < 4; ++ww) v += pbuf[(ww * 8 + r) * 64 + b];
        xp_out[((size_t)(bid * S + s) * 8 + r) * 64 + b] = v;
      }
    }
    __syncthreads();
  }
}

struct XpParams {
  const int* src; const int* tgt;
  const float* enc_emb; const float* dec_emb;
  const float* enc_Wih; const float* enc_bih; const float* enc_bhh;
  const float* dec_Wih; const float* dec_bih; const float* dec_bhh;
  float* xpe; float* xpd;
};

__global__ __launch_bounds__(256) void xp_k(XpParams p) {
  __shared__ __align__(16) float W_lds[8 * EDIM];
  __shared__ float pbuf[32 * 64];
  __shared__ float bias_lds[8];
  const int bid = blockIdx.x;
  if (bid < 256)
    xp_phase(p.src, SENC, SENC, p.enc_emb, p.enc_Wih, p.enc_bih, p.enc_bhh,
             p.xpe, bid, threadIdx.x, W_lds, pbuf, bias_lds);
  else
    xp_phase(p.tgt, 32, TDEC, p.dec_emb, p.dec_Wih, p.dec_bih, p.dec_bhh,
             p.xpd, bid - 256, threadIdx.x, W_lds, pbuf, bias_lds);
}

// ---------------- recurrence (cooperative, distributed-flag barrier) -------
// Sync protocol (proven R1/R2): h stores write-through (relaxed agent atomic
// store -> straight to MALL, no buffer_wbl2); vmcnt(0)+syncthreads before the
// per-block arrival flag (distributed dwords, zero RMW contention); wave 0
// polls all 256 flags in parallel; one acquire fence (buffer_inv) per step
// keeps h reads on the normal cached path.
// NEW (R3): the gate GEMM data paths are restructured.
//  * W is wave-uniform (no lane dependence) -> read via SCALAR loads from
//    global (K$-resident 16 KB/block working set), consuming zero VALU/LDS
//    issue slots. v_fmac_f32 takes the SGPR operand directly. This removes
//    the 8x ds_read_b128 per kk-iteration that made R2 LDS-issue-bound
//    (~119 cy LDS issue vs 64 cy VALU per iteration at 1 wave/SIMD).
//  * h goes straight to VGPRs: 64 coalesced global_load_dword bulk-issued
//    into a fully-unrolled hreg[64], then a pure-FMA loop (8 independent
//    acc chains). No LDS round-trip for single-use data.
//  * 512 threads/block (8 waves = 2/SIMD): wave pairs overlap load-wait with
//    FMA issue. LDS drops 156 KB -> 17 KB.
__device__ __forceinline__ void grid_barrier(unsigned* flags, unsigned gen) {
  asm volatile("s_waitcnt vmcnt(0)" ::: "memory");
  __syncthreads();
  const int tid = threadIdx.x;
  if (tid == 0)
    __hip_atomic_store(&flags[blockIdx.x], gen, __ATOMIC_RELAXED,
                       __HIP_MEMORY_SCOPE_AGENT);
  if (tid < 64) {
    const unsigned* f4 = flags + tid * 4;
    for (;;) {
      unsigned a = __hip_atomic_load(&f4[0], __ATOMIC_RELAXED, __HIP_MEMORY_SCOPE_AGENT);
      unsigned b = __hip_atomic_load(&f4[1], __ATOMIC_RELAXED, __HIP_MEMORY_SCOPE_AGENT);
      unsigned c = __hip_atomic_load(&f4[2], __ATOMIC_RELAXED, __HIP_MEMORY_SCOPE_AGENT);
      unsigned d = __hip_atomic_load(&f4[3], __ATOMIC_RELAXED, __HIP_MEMORY_SCOPE_AGENT);
      unsigned m0 = a < b ? a : b;
      unsigned m1 = c < d ? c : d;
      unsigned m = m0 < m1 ? m0 : m1;
      if (__all((int)(m >= gen))) break;
      __builtin_amdgcn_s_sleep(1);
    }
    __builtin_amdgcn_fence(__ATOMIC_ACQUIRE, "agent");
  }
  __syncthreads();
}

#define KW 64   // k-slice per wave (8 waves x 64 = HDIM)

__device__ __forceinline__ void recur_phase(const float* Whh, const float* xp,
                            int S, int gen0, int last_phase, int bid, int tid,
                            float* pbuf, float* c_lds,
                            float*& hp, float*& hn,
                            unsigned short* hs_or_null, unsigned* flags) {
  const int lane = tid & 63;
  const int wu = __builtin_amdgcn_readfirstlane(tid >> 6);  // wave id 0..7
  const int j0 = bid * 2;

  // wave-uniform W row base pointers -> scalar loads in the inner loop
  const float* Wr[8];
#pragma unroll
  for (int r = 0; r < 8; ++r)
    Wr[r] = Whh + (size_t)((r >> 1) * HDIM + j0 + (r & 1)) * HDIM + wu * KW;

  const int unit = tid >> 6;       // valid for tid < 128
  const int b = tid & 63;
  // preload xp gate inputs for s = 0 (registers survive the L2 invalidate)
  float xg[4];
  if (tid < 128) {
#pragma unroll
    for (int gate = 0; gate < 4; ++gate) {
      int r = gate * 2 + unit;
      xg[gate] = xp[((size_t)(bid * S) * 8 + r) * 64 + b];
    }
  }

  for (int s = 0; s < S; ++s) {
    // --- bulk-load this wave's h k-slice into registers (coalesced) ---
    float hreg[KW];
    const float* hb = hp + (size_t)wu * KW * 64 + lane;
#pragma unroll
    for (int k = 0; k < KW; ++k) hreg[k] = hb[k * 64];

    // --- pure-FMA GEMM slice: W from SGPRs (scalar loads), h from VGPRs ---
    float acc[8];
#pragma unroll
    for (int r = 0; r < 8; ++r) acc[r] = 0.0f;
#pragma unroll
    for (int k = 0; k < KW; ++k) {
#pragma unroll
      for (int r = 0; r < 8; ++r) acc[r] += Wr[r][k] * hreg[k];
    }
#pragma unroll
    for (int r = 0; r < 8; ++r) pbuf[(wu * 8 + r) * 64 + lane] = acc[r];
    __syncthreads();

    float xgn[4];
    if (tid < 128) {
      float g[4];
#pragma unroll
      for (int gate = 0; gate < 4; ++gate) {
        int r = gate * 2 + unit;
        float v = xg[gate];
#pragma unroll
        for (int ww = 0; ww < 8; ++ww) v += pbuf[(ww * 8 + r) * 64 + b];
        g[gate] = v;
      }
      float c = c_lds[unit * 64 + b];
      float iv = sigf(g[0]), fv = sigf(g[1]);
      float gv = tanhfast(g[2]), ov = sigf(g[3]);
      c = fv * c + iv * gv;
      float h = ov * tanhfast(c);
      c_lds[unit * 64 + b] = c;
      // write-through store: globally visible at MALL once vmcnt drains,
      // no L2 writeback needed on the release side
      __hip_atomic_store(&hn[(j0 + unit) * 64 + b], h, __ATOMIC_RELAXED,
                         __HIP_MEMORY_SCOPE_AGENT);
      if (hs_or_null)
        hs_or_null[((size_t)b * TDEC + s) * HDIM + j0 + unit] = f2bf(h);
      // prefetch next step's xp into registers; latency hides under the
      // barrier wait, and the values survive the acquire invalidate
      int sn = (s + 1 < S) ? s + 1 : s;
#pragma unroll
      for (int gate = 0; gate < 4; ++gate) {
        int r = gate * 2 + unit;
        xgn[gate] = xp[((size_t)(bid * S + sn) * 8 + r) * 64 + b];
      }
    }
    if (!(last_phase && s == S - 1))
      grid_barrier(flags, (unsigned)(gen0 + s + 1));
    if (tid < 128) {
#pragma unroll
      for (int gate = 0; gate < 4; ++gate) xg[gate] = xgn[gate];
    }
    float* tmp = hp; hp = hn; hn = tmp;
  }
}

struct RecurParams {
  const float* enc_Whh; const float* dec_Whh;
  const float* xpe; const float* xpd;
  float* hTA; float* hTB;
  unsigned short* hs;
  unsigned* flags;
};

__global__ __launch_bounds__(512, 2) void recur_coop(RecurParams p) {
  __shared__ float pbuf[64 * 64];                     // 16 KB (8 waves x 8 rows)
  __shared__ float c_lds[2 * 64];
  const int tid = threadIdx.x;
  const int bid = blockIdx.x;
  if (tid < 128) c_lds[tid] = 0.0f;
  __syncthreads();
  float* hp = p.hTA;
  float* hn = p.hTB;
  recur_phase(p.enc_Whh, p.xpe, SENC, 0, 0, bid, tid, pbuf, c_lds,
              hp, hn, nullptr, p.flags);
  recur_phase(p.dec_Whh, p.xpd, TDEC, SENC, 1, bid, tid, pbuf, c_lds,
              hp, hn, p.hs, p.flags);
}

// ---------------- FC head: logits = hs @ fcw^T + b ----------------
__global__ __launch_bounds__(256) void fc_gemm(const unsigned short* __restrict__ A,
                                               const unsigned short* __restrict__ Bm,
                                               const float* __restrict__ bias,
                                               float* __restrict__ out) {
  __shared__ __align__(16) unsigned short As[128 * 32];
  __shared__ __align__(16) unsigned short Bs[128 * 32];
  const int tid = threadIdx.x;
  const int lane = tid & 63;
  const int w = tid >> 6;
  const int m0 = blockIdx.y * 128;
  const int n0 = blockIdx.x * 128;
  const int wm = (w >> 1) * 64;
  const int wn = (w & 1) * 64;
  const int ml = lane & 15;
  const int kq = (lane >> 4) * 8;

  f32x4 acc[4][4] = {};

  for (int k0 = 0; k0 < HDIM; k0 += 32) {
    for (int c = tid; c < 512; c += 256) {
      int row = c >> 2;
      int ko = (c & 3) * 8;
      *(uint4*)&As[c * 8] = *(const uint4*)(A + (size_t)(m0 + row) * HDIM + k0 + ko);
      *(uint4*)&Bs[c * 8] = *(const uint4*)(Bm + (size_t)(n0 + row) * HDIM + k0 + ko);
    }
    __syncthreads();
    bf16x8 fa[4], fb[4];
#pragma unroll
    for (int i = 0; i < 4; ++i)
      fa[i] = *(const bf16x8*)&As[(wm + 16 * i + ml) * 32 + kq];
#pragma unroll
    for (int j = 0; j < 4; ++j)
      fb[j] = *(const bf16x8*)&Bs[(wn + 16 * j + ml) * 32 + kq];
#pragma unroll
    for (int i = 0; i < 4; ++i)
#pragma unroll
      for (int j = 0; j < 4; ++j)
        acc[i][j] = __builtin_amdgcn_mfma_f32_16x16x32_bf16(fa[i], fb[j], acc[i][j], 0, 0, 0);
    __syncthreads();
  }

  const int rq = (lane >> 4) * 4;
#pragma unroll
  for (int j = 0; j < 4; ++j) {
    int n = n0 + wn + 16 * j + ml;
    float bv = bias[n];
#pragma unroll
    for (int i = 0; i < 4; ++i) {
#pragma unroll
      for (int r = 0; r < 4; ++r) {
        int m = m0 + wm + 16 * i + rq + r;
        if (m < MROWS) {
          int b = m / TDEC;
          int t = m - b * TDEC;
          out[((size_t)(b * 32 + t + 1)) * VOCAB + n] = acc[i][j][r] + bv;
        }
      }
    }
  }
}

extern "C" void kernel_launch(void* const* d_in, const int* in_sizes, int n_in,
                              void* d_out, int out_size, void* d_ws, size_t ws_size,
                              hipStream_t stream) {
  (void)in_sizes; (void)n_in; (void)out_size; (void)ws_size;
  const int* src      = (const int*)d_in[0];
  const int* tgt      = (const int*)d_in[1];
  const float* enc_emb = (const float*)d_in[2];
  const float* dec_emb = (const float*)d_in[3];
  const float* enc_Wih = (const float*)d_in[4];
  const float* enc_Whh = (const float*)d_in[5];
  const float* enc_bih = (const float*)d_in[6];
  const float* enc_bhh = (const float*)d_in[7];
  const float* dec_Wih = (const float*)d_in[8];
  const float* dec_Whh = (const float*)d_in[9];
  const float* dec_bih = (const float*)d_in[10];
  const float* dec_bhh = (const float*)d_in[11];
  const float* fc_W    = (const float*)d_in[12];
  const float* fc_b    = (const float*)d_in[13];
  char* ws = (char*)d_ws;
  float* hTA = (float*)(ws + OFF_HTA);
  float* hTB = (float*)(ws + OFF_HTB);
  float* xpe = (float*)(ws + OFF_XPE);
  float* xpd = (float*)(ws + OFF_XPD);
  unsigned short* hs  = (unsigned short*)(ws + OFF_HS);
  unsigned short* fcw = (unsigned short*)(ws + OFF_FCW);
  unsigned* flags = (unsigned*)(ws + OFF_HS + (size_t)MROWS * HDIM * 2);
  float* out = (float*)d_out;

  hipLaunchKernelGGL(setup_k, dim3(2048), dim3(256), 0, stream, fc_W, fcw, hTA, hs, out);

  XpParams xq = { src, tgt, enc_emb, dec_emb, enc_Wih, enc_bih, enc_bhh,
                  dec_Wih, dec_bih, dec_bhh, xpe, xpd };
  hipLaunchKernelGGL(xp_k, dim3(512), dim3(256), 0, stream, xq);

  RecurParams rp = { enc_Whh, dec_Whh, xpe, xpd, hTA, hTB, hs, flags };
  void* args[] = { &rp };
  hipLaunchCooperativeKernel((const void*)recur_coop, dim3(NBLK), dim3(512), args, 0, stream);

  hipLaunchKernelGGL(fc_gemm, dim3(VOCAB / 128, MPAD / 128), dim3(256), 0, stream,
                     hs, fcw, fc_b, out);
}

// Round 4
// 2433.698 us; speedup vs baseline: 1.0496x; 1.0496x over previous
//
#include <hip/hip_runtime.h>
#include <cstdint>
#include <cstddef>

// Problem dims
#define NB    64      // batch
#define SENC  64      // encoder steps
#define TDEC  31      // decoder steps (tgt[:, :-1])
#define EDIM  256
#define HDIM  512
#define VOCAB 32000
#define MROWS (NB * TDEC)   // 1984
#define MPAD  2048
#define NBLK  256           // recurrence grid (cooperative)
#define KW    32            // k-slice per wave (16 waves x 32 = HDIM)

// workspace byte offsets
#define OFF_HTA  0
#define OFF_HTB  (OFF_HTA + HDIM * NB * 4)
#define OFF_XPE  (OFF_HTB + HDIM * NB * 4)
#define OFF_XPD  (OFF_XPE + 256 * SENC * 8 * NB * 4)
#define OFF_HS   (OFF_XPD + 256 * TDEC * 8 * NB * 4)
#define OFF_FCW  (OFF_HS + MPAD * HDIM * 2)
// barrier flag array (NBLK u32 = 1 KB) overlays the first bytes of the hs PAD
// rows (rows MROWS..MPAD-1). Those rows only feed fc_gemm output rows
// m>=MROWS, which are discarded by the m<MROWS guard — garbage is harmless.

typedef __attribute__((ext_vector_type(8))) short bf16x8;   // 8 bf16 (4 VGPRs)
typedef __attribute__((ext_vector_type(4))) float f32x4;

__device__ __forceinline__ float sigf(float x) { return 1.0f / (1.0f + __expf(-x)); }
__device__ __forceinline__ float tanhfast(float x) {
  return 1.0f - 2.0f / (__expf(2.0f * x) + 1.0f);
}
__device__ __forceinline__ unsigned short f2bf(float x) {
  unsigned int u = __float_as_uint(x);
  u += 0x7fffu + ((u >> 16) & 1u);   // RNE
  return (unsigned short)(u >> 16);
}
__device__ __forceinline__ unsigned pack2(float a, float b) {
  return (unsigned)f2bf(a) | ((unsigned)f2bf(b) << 16);
}

// ---------------- setup: fcw bf16 convert + zeros ----------------
__global__ __launch_bounds__(256) void setup_k(const float* __restrict__ fc_W,
                                               unsigned short* __restrict__ fcw,
                                               float* __restrict__ hTA,
                                               unsigned short* __restrict__ hs,
                                               float* __restrict__ out) {
  const int gt = blockIdx.x * 256 + threadIdx.x;
  const int GSZ = 2048 * 256;
  const float4* s4 = (const float4*)fc_W;
  uint4* d4 = (uint4*)fcw;
  for (int i = gt; i < (VOCAB * HDIM / 8); i += GSZ) {
    float4 x = s4[2 * i], y = s4[2 * i + 1];
    uint4 v;
    v.x = pack2(x.x, x.y); v.y = pack2(x.z, x.w);
    v.z = pack2(y.x, y.y); v.w = pack2(y.z, y.w);
    d4[i] = v;
  }
  float4 z4 = make_float4(0.f, 0.f, 0.f, 0.f);
  // out[:,0,:] = 0
  for (int j = gt; j < NB * (VOCAB / 4); j += GSZ) {
    int b = j / (VOCAB / 4), q = j - b * (VOCAB / 4);
    ((float4*)out)[(size_t)b * (32 * (VOCAB / 4)) + q] = z4;
  }
  if (gt < HDIM * NB / 4) ((float4*)hTA)[gt] = z4;
  // hs pad rows (also zeroes the overlaid barrier flag array)
  if (gt < (MPAD - MROWS) * HDIM / 8) {
    uint4 uz = {0u, 0u, 0u, 0u};
    ((uint4*)(hs + (size_t)MROWS * HDIM))[gt] = uz;
  }
}

// ---------------- xp: input projections ----------------
// xp[s][r][b] = bias_r + sum_e Wih[row_g(r)][e] * emb[idx[b][s]][e]
__device__ void xp_phase(const int* idxmat, int istride, int S,
                         const float* emb, const float* Wih,
                         const float* bih, const float* bhh,
                         float* xp_out, int bid, int tid,
                         float* W_lds, float* pbuf, float* bias_lds) {
  const int lane = tid & 63;
  const int w = tid >> 6;
  {
    int r = tid >> 5;                  // 0..7
    int e0 = (tid & 31) * 8;           // 0..248
    int row_g = (r >> 1) * HDIM + bid * 2 + (r & 1);
    const float* sp = Wih + (size_t)row_g * EDIM + e0;
    *(float4*)&W_lds[r * EDIM + e0]     = *(const float4*)sp;
    *(float4*)&W_lds[r * EDIM + e0 + 4] = *(const float4*)(sp + 4);
    if (tid < 8) {
      int rg = (tid >> 1) * HDIM + bid * 2 + (tid & 1);
      bias_lds[tid] = bih[rg] + bhh[rg];
    }
  }
  __syncthreads();
  for (int s = 0; s < S; ++s) {
    int idx = idxmat[lane * istride + s];
    const float* xrow = emb + (size_t)idx * EDIM;
    float acc[8];
#pragma unroll
    for (int r = 0; r < 8; ++r) acc[r] = 0.0f;
    for (int e = w * 64; e < w * 64 + 64; e += 4) {
      float4 xv = *(const float4*)&xrow[e];
#pragma unroll
      for (int r = 0; r < 8; ++r) {
        float4 wv = *(const float4*)&W_lds[r * EDIM + e];
        acc[r] += wv.x * xv.x + wv.y * xv.y + wv.z * xv.z + wv.w * xv.w;
      }
    }
#pragma unroll
    for (int r = 0; r < 8; ++r) pbuf[(w * 8 + r) * 64 + lane] = acc[r];
    __syncthreads();
    if (tid < 128) {
      int unit = tid >> 6, b = tid & 63;
#pragma unroll
      for (int gate = 0; gate < 4; ++gate) {
        int r = gate * 2 + unit;
        float v = bias_lds[r];
#pragma unroll
        for (int ww = 0; ww < 4; ++ww) v += pbuf[(ww * 8 + r) * 64 + b];
        xp_out[((size_t)(bid * S + s) * 8 + r) * 64 + b] = v;
      }
    }
    __syncthreads();
  }
}

struct XpParams {
  const int* src; const int* tgt;
  const float* enc_emb; const float* dec_emb;
  const float* enc_Wih; const float* enc_bih; const float* enc_bhh;
  const float* dec_Wih; const float* dec_bih; const float* dec_bhh;
  float* xpe; float* xpd;
};

__global__ __launch_bounds__(256) void xp_k(XpParams p) {
  __shared__ __align__(16) float W_lds[8 * EDIM];
  __shared__ float pbuf[32 * 64];
  __shared__ float bias_lds[8];
  const int bid = blockIdx.x;
  if (bid < 256)
    xp_phase(p.src, SENC, SENC, p.enc_emb, p.enc_Wih, p.enc_bih, p.enc_bhh,
             p.xpe, bid, threadIdx.x, W_lds, pbuf, bias_lds);
  else
    xp_phase(p.tgt, 32, TDEC, p.dec_emb, p.dec_Wih, p.dec_bih, p.dec_bhh,
             p.xpd, bid - 256, threadIdx.x, W_lds, pbuf, bias_lds);
}

// ---------------- recurrence (cooperative, fence-free MALL protocol) -------
// R4 protocol: NO acquire fence, NO L2 invalidate, ever.
//  * h stores: write-through relaxed agent atomic stores -> land at the MALL
//    (coherence point). vmcnt(0)+syncthreads before the flag store orders
//    them ahead of the arrival flag.
//  * h loads: relaxed agent atomic loads -> BYPASS the (non-coherent) L2 and
//    read the MALL directly. A wave issues vector-memory ops in program
//    order, so h loads issued after the poll observed the flag reach the
//    MALL strictly after the writer's data landed there. No fence needed.
//  * Everything else (W via scalar loads, xp, hs) uses the normal cached
//    path and now stays L1/L2/K$-resident across ALL 95 steps — R3's
//    per-step buffer_inv was forcing a full refetch of W (4 MB grid-wide)
//    and the 32 MB/step h broadcast from MALL/HBM every single step, with
//    serialized scalar-K$ misses gating the FMA loop. That was the
//    compute-invariant 14 µs/step floor of R1-R3.
//  * 1024 threads/block (16 waves = 4/SIMD) to hide MALL load latency.
__device__ __forceinline__ void grid_barrier(unsigned* flags, unsigned gen) {
  asm volatile("s_waitcnt vmcnt(0)" ::: "memory");
  __syncthreads();
  const int tid = threadIdx.x;
  if (tid == 0)
    __hip_atomic_store(&flags[blockIdx.x], gen, __ATOMIC_RELAXED,
                       __HIP_MEMORY_SCOPE_AGENT);
  if (tid < 64) {
    const unsigned* f4 = flags + tid * 4;
    for (;;) {
      unsigned a = __hip_atomic_load(&f4[0], __ATOMIC_RELAXED, __HIP_MEMORY_SCOPE_AGENT);
      unsigned b = __hip_atomic_load(&f4[1], __ATOMIC_RELAXED, __HIP_MEMORY_SCOPE_AGENT);
      unsigned c = __hip_atomic_load(&f4[2], __ATOMIC_RELAXED, __HIP_MEMORY_SCOPE_AGENT);
      unsigned d = __hip_atomic_load(&f4[3], __ATOMIC_RELAXED, __HIP_MEMORY_SCOPE_AGENT);
      unsigned m0 = a < b ? a : b;
      unsigned m1 = c < d ? c : d;
      unsigned m = m0 < m1 ? m0 : m1;
      if (__all((int)(m >= gen))) break;
      __builtin_amdgcn_s_sleep(1);
    }
  }
  __syncthreads();
}

__device__ __forceinline__ void recur_phase(const float* Whh, const float* xp,
                            int S, int gen0, int last_phase, int bid, int tid,
                            float* pbuf, float* c_lds,
                            float*& hp, float*& hn,
                            unsigned short* hs_or_null, unsigned* flags) {
  const int lane = tid & 63;
  const int wu = __builtin_amdgcn_readfirstlane(tid >> 6);  // wave id 0..15
  const int j0 = bid * 2;

  // wave-uniform W row base pointers -> scalar loads in the inner loop
  // (K$-resident after step 0: no fence ever invalidates them)
  const float* Wr[8];
#pragma unroll
  for (int r = 0; r < 8; ++r)
    Wr[r] = Whh + (size_t)((r >> 1) * HDIM + j0 + (r & 1)) * HDIM + wu * KW;

  const int unit = tid >> 6;       // valid for tid < 128
  const int b = tid & 63;
  // preload xp gate inputs for s = 0
  float xg[4];
  if (tid < 128) {
#pragma unroll
    for (int gate = 0; gate < 4; ++gate) {
      int r = gate * 2 + unit;
      xg[gate] = xp[((size_t)(bid * S) * 8 + r) * 64 + b];
    }
  }

  for (int s = 0; s < S; ++s) {
    // --- bulk-load this wave's h k-slice into registers via MALL-coherent
    //     (L2-bypassing) loads; coalesced 256B per instruction ---
    float hreg[KW];
    const float* hb = hp + (size_t)wu * KW * 64 + lane;
#pragma unroll
    for (int k = 0; k < KW; ++k)
      hreg[k] = __hip_atomic_load(&hb[k * 64], __ATOMIC_RELAXED,
                                  __HIP_MEMORY_SCOPE_AGENT);

    // --- pure-FMA GEMM slice: W from SGPRs (scalar loads), h from VGPRs ---
    float acc[8];
#pragma unroll
    for (int r = 0; r < 8; ++r) acc[r] = 0.0f;
#pragma unroll
    for (int k = 0; k < KW; ++k) {
#pragma unroll
      for (int r = 0; r < 8; ++r) acc[r] += Wr[r][k] * hreg[k];
    }
#pragma unroll
    for (int r = 0; r < 8; ++r) pbuf[(wu * 8 + r) * 64 + lane] = acc[r];
    __syncthreads();

    float xgn[4];
    if (tid < 128) {
      float g[4];
#pragma unroll
      for (int gate = 0; gate < 4; ++gate) {
        int r = gate * 2 + unit;
        float v = xg[gate];
#pragma unroll
        for (int ww = 0; ww < 16; ++ww) v += pbuf[(ww * 8 + r) * 64 + b];
        g[gate] = v;
      }
      float c = c_lds[unit * 64 + b];
      float iv = sigf(g[0]), fv = sigf(g[1]);
      float gv = tanhfast(g[2]), ov = sigf(g[3]);
      c = fv * c + iv * gv;
      float h = ov * tanhfast(c);
      c_lds[unit * 64 + b] = c;
      // write-through store: lands at the MALL; vmcnt drain in grid_barrier
      // orders it before the flag
      __hip_atomic_store(&hn[(j0 + unit) * 64 + b], h, __ATOMIC_RELAXED,
                         __HIP_MEMORY_SCOPE_AGENT);
      if (hs_or_null)
        hs_or_null[((size_t)b * TDEC + s) * HDIM + j0 + unit] = f2bf(h);
      // prefetch next step's xp (normal cached path, L2-resident)
      int sn = (s + 1 < S) ? s + 1 : s;
#pragma unroll
      for (int gate = 0; gate < 4; ++gate) {
        int r = gate * 2 + unit;
        xgn[gate] = xp[((size_t)(bid * S + sn) * 8 + r) * 64 + b];
      }
    }
    if (!(last_phase && s == S - 1))
      grid_barrier(flags, (unsigned)(gen0 + s + 1));
    if (tid < 128) {
#pragma unroll
      for (int gate = 0; gate < 4; ++gate) xg[gate] = xgn[gate];
    }
    float* tmp = hp; hp = hn; hn = tmp;
  }
}

struct RecurParams {
  const float* enc_Whh; const float* dec_Whh;
  const float* xpe; const float* xpd;
  float* hTA; float* hTB;
  unsigned short* hs;
  unsigned* flags;
};

__global__ __launch_bounds__(1024, 1) void recur_coop(RecurParams p) {
  __shared__ float pbuf[128 * 64];                    // 32 KB (16 waves x 8 rows)
  __shared__ float c_lds[2 * 64];
  const int tid = threadIdx.x;
  const int bid = blockIdx.x;
  if (tid < 128) c_lds[tid] = 0.0f;
  __syncthreads();
  float* hp = p.hTA;
  float* hn = p.hTB;
  recur_phase(p.enc_Whh, p.xpe, SENC, 0, 0, bid, tid, pbuf, c_lds,
              hp, hn, nullptr, p.flags);
  recur_phase(p.dec_Whh, p.xpd, TDEC, SENC, 1, bid, tid, pbuf, c_lds,
              hp, hn, p.hs, p.flags);
}

// ---------------- FC head: logits = hs @ fcw^T + b ----------------
__global__ __launch_bounds__(256) void fc_gemm(const unsigned short* __restrict__ A,
                                               const unsigned short* __restrict__ Bm,
                                               const float* __restrict__ bias,
                                               float* __restrict__ out) {
  __shared__ __align__(16) unsigned short As[128 * 32];
  __shared__ __align__(16) unsigned short Bs[128 * 32];
  const int tid = threadIdx.x;
  const int lane = tid & 63;
  const int w = tid >> 6;
  const int m0 = blockIdx.y * 128;
  const int n0 = blockIdx.x * 128;
  const int wm = (w >> 1) * 64;
  const int wn = (w & 1) * 64;
  const int ml = lane & 15;
  const int kq = (lane >> 4) * 8;

  f32x4 acc[4][4] = {};

  for (int k0 = 0; k0 < HDIM; k0 += 32) {
    for (int c = tid; c < 512; c += 256) {
      int row = c >> 2;
      int ko = (c & 3) * 8;
      *(uint4*)&As[c * 8] = *(const uint4*)(A + (size_t)(m0 + row) * HDIM + k0 + ko);
      *(uint4*)&Bs[c * 8] = *(const uint4*)(Bm + (size_t)(n0 + row) * HDIM + k0 + ko);
    }
    __syncthreads();
    bf16x8 fa[4], fb[4];
#pragma unroll
    for (int i = 0; i < 4; ++i)
      fa[i] = *(const bf16x8*)&As[(wm + 16 * i + ml) * 32 + kq];
#pragma unroll
    for (int j = 0; j < 4; ++j)
      fb[j] = *(const bf16x8*)&Bs[(wn + 16 * j + ml) * 32 + kq];
#pragma unroll
    for (int i = 0; i < 4; ++i)
#pragma unroll
      for (int j = 0; j < 4; ++j)
        acc[i][j] = __builtin_amdgcn_mfma_f32_16x16x32_bf16(fa[i], fb[j], acc[i][j], 0, 0, 0);
    __syncthreads();
  }

  const int rq = (lane >> 4) * 4;
#pragma unroll
  for (int j = 0; j < 4; ++j) {
    int n = n0 + wn + 16 * j + ml;
    float bv = bias[n];
#pragma unroll
    for (int i = 0; i < 4; ++i) {
#pragma unroll
      for (int r = 0; r < 4; ++r) {
        int m = m0 + wm + 16 * i + rq + r;
        if (m < MROWS) {
          int b = m / TDEC;
          int t = m - b * TDEC;
          out[((size_t)(b * 32 + t + 1)) * VOCAB + n] = acc[i][j][r] + bv;
        }
      }
    }
  }
}

extern "C" void kernel_launch(void* const* d_in, const int* in_sizes, int n_in,
                              void* d_out, int out_size, void* d_ws, size_t ws_size,
                              hipStream_t stream) {
  (void)in_sizes; (void)n_in; (void)out_size; (void)ws_size;
  const int* src      = (const int*)d_in[0];
  const int* tgt      = (const int*)d_in[1];
  const float* enc_emb = (const float*)d_in[2];
  const float* dec_emb = (const float*)d_in[3];
  const float* enc_Wih = (const float*)d_in[4];
  const float* enc_Whh = (const float*)d_in[5];
  const float* enc_bih = (const float*)d_in[6];
  const float* enc_bhh = (const float*)d_in[7];
  const float* dec_Wih = (const float*)d_in[8];
  const float* dec_Whh = (const float*)d_in[9];
  const float* dec_bih = (const float*)d_in[10];
  const float* dec_bhh = (const float*)d_in[11];
  const float* fc_W    = (const float*)d_in[12];
  const float* fc_b    = (const float*)d_in[13];
  char* ws = (char*)d_ws;
  float* hTA = (float*)(ws + OFF_HTA);
  float* hTB = (float*)(ws + OFF_HTB);
  float* xpe = (float*)(ws + OFF_XPE);
  float* xpd = (float*)(ws + OFF_XPD);
  unsigned short* hs  = (unsigned short*)(ws + OFF_HS);
  unsigned short* fcw = (unsigned short*)(ws + OFF_FCW);
  unsigned* flags = (unsigned*)(ws + OFF_HS + (size_t)MROWS * HDIM * 2);
  float* out = (float*)d_out;

  hipLaunchKernelGGL(setup_k, dim3(2048), dim3(256), 0, stream, fc_W, fcw, hTA, hs, out);

  XpParams xq = { src, tgt, enc_emb, dec_emb, enc_Wih, enc_bih, enc_bhh,
                  dec_Wih, dec_bih, dec_bhh, xpe, xpd };
  hipLaunchKernelGGL(xp_k, dim3(512), dim3(256), 0, stream, xq);

  RecurParams rp = { enc_Whh, dec_Whh, xpe, xpd, hTA, hTB, hs, flags };
  void* args[] = { &rp };
  hipLaunchCooperativeKernel((const void*)recur_coop, dim3(NBLK), dim3(1024), args, 0, stream);

  hipLaunchKernelGGL(fc_gemm, dim3(VOCAB / 128, MPAD / 128), dim3(256), 0, stream,
                     hs, fcw, fc_b, out);
}

// Round 5
// 2407.365 us; speedup vs baseline: 1.0611x; 1.0109x over previous
//
#include <hip/hip_runtime.h>
#include <cstdint>
#include <cstddef>

// Problem dims
#define NB    64      // batch
#define SENC  64      // encoder steps
#define TDEC  31      // decoder steps (tgt[:, :-1])
#define EDIM  256
#define HDIM  512
#define VOCAB 32000
#define MROWS (NB * TDEC)   // 1984
#define MPAD  2048
#define NBLK  256           // recurrence grid (cooperative)
#define KW    32            // k-slice per wave (16 waves x 32 = HDIM)

// h history: one 128 KB slot per global step (+1 for the initial zeros).
// A slot is written exactly once (write-through to MALL) and only read after
// the barrier for its generation -> reader L1/L2 lines are always COLD for a
// slot's first read, so plain cached loads are guaranteed-fresh with NO fence
// and NO invalidate. Blocks on the same XCD then share one L2 copy of h
// (cross-L2 traffic 32 MB/step -> 1 MB/step).
#define HSLOT (HDIM * NB)   // floats per slot (32768)
#define NSLOT 96            // SENC + TDEC + 1 = 96

// workspace byte offsets
#define OFF_HH   0
#define OFF_XPE  (OFF_HH + NSLOT * HSLOT * 4)
#define OFF_XPD  (OFF_XPE + 256 * SENC * 8 * NB * 4)
#define OFF_HS   (OFF_XPD + 256 * TDEC * 8 * NB * 4)
#define OFF_FCW  (OFF_HS + MPAD * HDIM * 2)
// barrier flag array (NBLK u32 = 1 KB) overlays the first bytes of the hs PAD
// rows (rows MROWS..MPAD-1). Those rows only feed fc_gemm output rows
// m>=MROWS, which are discarded by the m<MROWS guard — garbage is harmless.

typedef __attribute__((ext_vector_type(8))) short bf16x8;   // 8 bf16 (4 VGPRs)
typedef __attribute__((ext_vector_type(4))) float f32x4;

__device__ __forceinline__ float sigf(float x) { return 1.0f / (1.0f + __expf(-x)); }
__device__ __forceinline__ float tanhfast(float x) {
  return 1.0f - 2.0f / (__expf(2.0f * x) + 1.0f);
}
__device__ __forceinline__ unsigned short f2bf(float x) {
  unsigned int u = __float_as_uint(x);
  u += 0x7fffu + ((u >> 16) & 1u);   // RNE
  return (unsigned short)(u >> 16);
}
__device__ __forceinline__ unsigned pack2(float a, float b) {
  return (unsigned)f2bf(a) | ((unsigned)f2bf(b) << 16);
}

// ---------------- setup: fcw bf16 convert + zeros ----------------
__global__ __launch_bounds__(256) void setup_k(const float* __restrict__ fc_W,
                                               unsigned short* __restrict__ fcw,
                                               float* __restrict__ hh,
                                               unsigned short* __restrict__ hs,
                                               float* __restrict__ out) {
  const int gt = blockIdx.x * 256 + threadIdx.x;
  const int GSZ = 2048 * 256;
  const float4* s4 = (const float4*)fc_W;
  uint4* d4 = (uint4*)fcw;
  for (int i = gt; i < (VOCAB * HDIM / 8); i += GSZ) {
    float4 x = s4[2 * i], y = s4[2 * i + 1];
    uint4 v;
    v.x = pack2(x.x, x.y); v.y = pack2(x.z, x.w);
    v.z = pack2(y.x, y.y); v.w = pack2(y.z, y.w);
    d4[i] = v;
  }
  float4 z4 = make_float4(0.f, 0.f, 0.f, 0.f);
  // out[:,0,:] = 0
  for (int j = gt; j < NB * (VOCAB / 4); j += GSZ) {
    int b = j / (VOCAB / 4), q = j - b * (VOCAB / 4);
    ((float4*)out)[(size_t)b * (32 * (VOCAB / 4)) + q] = z4;
  }
  // h_hist slot 0 = h0 = zeros
  if (gt < HSLOT / 4) ((float4*)hh)[gt] = z4;
  // hs pad rows (also zeroes the overlaid barrier flag array)
  if (gt < (MPAD - MROWS) * HDIM / 8) {
    uint4 uz = {0u, 0u, 0u, 0u};
    ((uint4*)(hs + (size_t)MROWS * HDIM))[gt] = uz;
  }
}

// ---------------- xp: input projections ----------------
// xp[s][r][b] = bias_r + sum_e Wih[row_g(r)][e] * emb[idx[b][s]][e]
__device__ void xp_phase(const int* idxmat, int istride, int S,
                         const float* emb, const float* Wih,
                         const float* bih, const float* bhh,
                         float* xp_out, int bid, int tid,
                         float* W_lds, float* pbuf, float* bias_lds) {
  const int lane = tid & 63;
  const int w = tid >> 6;
  {
    int r = tid >> 5;                  // 0..7
    int e0 = (tid & 31) * 8;           // 0..248
    int row_g = (r >> 1) * HDIM + bid * 2 + (r & 1);
    const float* sp = Wih + (size_t)row_g * EDIM + e0;
    *(float4*)&W_lds[r * EDIM + e0]     = *(const float4*)sp;
    *(float4*)&W_lds[r * EDIM + e0 + 4] = *(const float4*)(sp + 4);
    if (tid < 8) {
      int rg = (tid >> 1) * HDIM + bid * 2 + (tid & 1);
      bias_lds[tid] = bih[rg] + bhh[rg];
    }
  }
  __syncthreads();
  for (int s = 0; s < S; ++s) {
    int idx = idxmat[lane * istride + s];
    const float* xrow = emb + (size_t)idx * EDIM;
    float acc[8];
#pragma unroll
    for (int r = 0; r < 8; ++r) acc[r] = 0.0f;
    for (int e = w * 64; e < w * 64 + 64; e += 4) {
      float4 xv = *(const float4*)&xrow[e];
#pragma unroll
      for (int r = 0; r < 8; ++r) {
        float4 wv = *(const float4*)&W_lds[r * EDIM + e];
        acc[r] += wv.x * xv.x + wv.y * xv.y + wv.z * xv.z + wv.w * xv.w;
      }
    }
#pragma unroll
    for (int r = 0; r < 8; ++r) pbuf[(w * 8 + r) * 64 + lane] = acc[r];
    __syncthreads();
    if (tid < 128) {
      int unit = tid >> 6, b = tid & 63;
#pragma unroll
      for (int gate = 0; gate < 4; ++gate) {
        int r = gate * 2 + unit;
        float v = bias_lds[r];
#pragma unroll
        for (int ww = 0; ww < 4; ++ww) v += pbuf[(ww * 8 + r) * 64 + b];
        xp_out[((size_t)(bid * S + s) * 8 + r) * 64 + b] = v;
      }
    }
    __syncthreads();
  }
}

struct XpParams {
  const int* src; const int* tgt;
  const float* enc_emb; const float* dec_emb;
  const float* enc_Wih; const float* enc_bih; const float* enc_bhh;
  const float* dec_Wih; const float* dec_bih; const float* dec_bhh;
  float* xpe; float* xpd;
};

__global__ __launch_bounds__(256) void xp_k(XpParams p) {
  __shared__ __align__(16) float W_lds[8 * EDIM];
  __shared__ float pbuf[32 * 64];
  __shared__ float bias_lds[8];
  const int bid = blockIdx.x;
  if (bid < 256)
    xp_phase(p.src, SENC, SENC, p.enc_emb, p.enc_Wih, p.enc_bih, p.enc_bhh,
             p.xpe, bid, threadIdx.x, W_lds, pbuf, bias_lds);
  else
    xp_phase(p.tgt, 32, TDEC, p.dec_emb, p.dec_Wih, p.dec_bih, p.dec_bhh,
             p.xpd, bid - 256, threadIdx.x, W_lds, pbuf, bias_lds);
}

// ---------------- recurrence (cooperative, h-history protocol) -------------
// R5: h reads are PLAIN CACHED loads of never-before-touched addresses
// (h_hist slot per step). Writers use write-through relaxed-agent atomic
// stores (land at MALL); vmcnt(0)+syncthreads orders them before the arrival
// flag; readers' first touch of a slot must miss L1/L2 and fetch the fresh
// data from MALL. No fence, no invalidate, and blocks sharing an XCD share
// one L2 copy of h — the 32 MB/step beyond-L2 broadcast of R1-R4 (the
// compute-invariant ~14 µs/step floor) becomes ~1 MB/step.
__device__ __forceinline__ void grid_barrier(unsigned* flags, unsigned gen) {
  asm volatile("s_waitcnt vmcnt(0)" ::: "memory");
  __syncthreads();
  const int tid = threadIdx.x;
  if (tid == 0)
    __hip_atomic_store(&flags[blockIdx.x], gen, __ATOMIC_RELAXED,
                       __HIP_MEMORY_SCOPE_AGENT);
  if (tid < 64) {
    const unsigned* f4 = flags + tid * 4;
    for (;;) {
      unsigned a = __hip_atomic_load(&f4[0], __ATOMIC_RELAXED, __HIP_MEMORY_SCOPE_AGENT);
      unsigned b = __hip_atomic_load(&f4[1], __ATOMIC_RELAXED, __HIP_MEMORY_SCOPE_AGENT);
      unsigned c = __hip_atomic_load(&f4[2], __ATOMIC_RELAXED, __HIP_MEMORY_SCOPE_AGENT);
      unsigned d = __hip_atomic_load(&f4[3], __ATOMIC_RELAXED, __HIP_MEMORY_SCOPE_AGENT);
      unsigned m0 = a < b ? a : b;
      unsigned m1 = c < d ? c : d;
      unsigned m = m0 < m1 ? m0 : m1;
      if (__all((int)(m >= gen))) break;
      __builtin_amdgcn_s_sleep(1);
    }
  }
  __syncthreads();
}

__device__ __forceinline__ void recur_phase(const float* Whh, const float* xp,
                            int S, int gen0, int last_phase, int bid, int tid,
                            float* pbuf, float* gsum, float* c_lds,
                            float* hh,
                            unsigned short* hs_or_null, unsigned* flags) {
  const int lane = tid & 63;
  const int wu = __builtin_amdgcn_readfirstlane(tid >> 6);  // wave id 0..15
  const int j0 = bid * 2;

  // wave-uniform W row base pointers -> scalar loads in the inner loop
  // (K$-resident across all steps: nothing ever invalidates them)
  const float* Wr[8];
#pragma unroll
  for (int r = 0; r < 8; ++r)
    Wr[r] = Whh + (size_t)((r >> 1) * HDIM + j0 + (r & 1)) * HDIM + wu * KW;

  const int unit = tid >> 6;       // valid for tid < 128
  const int b = tid & 63;
  // preload xp gate inputs for s = 0
  float xg[4];
  if (tid < 128) {
#pragma unroll
    for (int gate = 0; gate < 4; ++gate) {
      int r = gate * 2 + unit;
      xg[gate] = xp[((size_t)(bid * S) * 8 + r) * 64 + b];
    }
  }

  for (int s = 0; s < S; ++s) {
    const float* hp = hh + (size_t)(gen0 + s) * HSLOT;
    float* hn = hh + (size_t)(gen0 + s + 1) * HSLOT;

    // --- bulk-load this wave's h k-slice: plain cached loads of cold
    //     addresses (L2-shared within the XCD), coalesced 256B/instr ---
    float hreg[KW];
    const float* hb = hp + (size_t)wu * KW * 64 + lane;
#pragma unroll
    for (int k = 0; k < KW; ++k) hreg[k] = hb[k * 64];

    // --- pure-FMA GEMM slice: W from SGPRs (scalar loads), h from VGPRs ---
    float acc[8];
#pragma unroll
    for (int r = 0; r < 8; ++r) acc[r] = 0.0f;
#pragma unroll
    for (int k = 0; k < KW; ++k) {
#pragma unroll
      for (int r = 0; r < 8; ++r) acc[r] += Wr[r][k] * hreg[k];
    }
#pragma unroll
    for (int r = 0; r < 8; ++r) pbuf[(wu * 8 + r) * 64 + lane] = acc[r];
    __syncthreads();

    // --- stage A: 512-thread cross-wave reduction (16 partials/row) ---
    if (tid < 512) {
      int row = tid >> 6, bb = tid & 63;
      float v = 0.0f;
#pragma unroll
      for (int ww = 0; ww < 16; ++ww) v += pbuf[(ww * 8 + row) * 64 + bb];
      gsum[row * 64 + bb] = v;
    }
    __syncthreads();

    // --- stage B: gates, state update, write-through h store ---
    float xgn[4];
    if (tid < 128) {
      float g[4];
#pragma unroll
      for (int gate = 0; gate < 4; ++gate)
        g[gate] = xg[gate] + gsum[(gate * 2 + unit) * 64 + b];
      float c = c_lds[unit * 64 + b];
      float iv = sigf(g[0]), fv = sigf(g[1]);
      float gv = tanhfast(g[2]), ov = sigf(g[3]);
      c = fv * c + iv * gv;
      float h = ov * tanhfast(c);
      c_lds[unit * 64 + b] = c;
      // write-through store: lands at the MALL; vmcnt drain in grid_barrier
      // orders it before the flag
      __hip_atomic_store(&hn[(j0 + unit) * 64 + b], h, __ATOMIC_RELAXED,
                         __HIP_MEMORY_SCOPE_AGENT);
      if (hs_or_null)
        hs_or_null[((size_t)b * TDEC + s) * HDIM + j0 + unit] = f2bf(h);
      // prefetch next step's xp (normal cached path, stays resident)
      int sn = (s + 1 < S) ? s + 1 : s;
#pragma unroll
      for (int gate = 0; gate < 4; ++gate) {
        int r = gate * 2 + unit;
        xgn[gate] = xp[((size_t)(bid * S + sn) * 8 + r) * 64 + b];
      }
    }
    if (!(last_phase && s == S - 1))
      grid_barrier(flags, (unsigned)(gen0 + s + 1));
    if (tid < 128) {
#pragma unroll
      for (int gate = 0; gate < 4; ++gate) xg[gate] = xgn[gate];
    }
  }
}

struct RecurParams {
  const float* enc_Whh; const float* dec_Whh;
  const float* xpe; const float* xpd;
  float* hh;
  unsigned short* hs;
  unsigned* flags;
};

__global__ __launch_bounds__(1024, 1) void recur_coop(RecurParams p) {
  __shared__ float pbuf[128 * 64];                    // 32 KB (16 waves x 8 rows)
  __shared__ float gsum[8 * 64];                      // 2 KB
  __shared__ float c_lds[2 * 64];
  const int tid = threadIdx.x;
  const int bid = blockIdx.x;
  if (tid < 128) c_lds[tid] = 0.0f;
  __syncthreads();
  recur_phase(p.enc_Whh, p.xpe, SENC, 0, 0, bid, tid, pbuf, gsum, c_lds,
              p.hh, nullptr, p.flags);
  recur_phase(p.dec_Whh, p.xpd, TDEC, SENC, 1, bid, tid, pbuf, gsum, c_lds,
              p.hh, p.hs, p.flags);
}

// ---------------- FC head: logits = hs @ fcw^T + b ----------------
__global__ __launch_bounds__(256) void fc_gemm(const unsigned short* __restrict__ A,
                                               const unsigned short* __restrict__ Bm,
                                               const float* __restrict__ bias,
                                               float* __restrict__ out) {
  __shared__ __align__(16) unsigned short As[128 * 32];
  __shared__ __align__(16) unsigned short Bs[128 * 32];
  const int tid = threadIdx.x;
  const int lane = tid & 63;
  const int w = tid >> 6;
  const int m0 = blockIdx.y * 128;
  const int n0 = blockIdx.x * 128;
  const int wm = (w >> 1) * 64;
  const int wn = (w & 1) * 64;
  const int ml = lane & 15;
  const int kq = (lane >> 4) * 8;

  f32x4 acc[4][4] = {};

  for (int k0 = 0; k0 < HDIM; k0 += 32) {
    for (int c = tid; c < 512; c += 256) {
      int row = c >> 2;
      int ko = (c & 3) * 8;
      *(uint4*)&As[c * 8] = *(const uint4*)(A + (size_t)(m0 + row) * HDIM + k0 + ko);
      *(uint4*)&Bs[c * 8] = *(const uint4*)(Bm + (size_t)(n0 + row) * HDIM + k0 + ko);
    }
    __syncthreads();
    bf16x8 fa[4], fb[4];
#pragma unroll
    for (int i = 0; i < 4; ++i)
      fa[i] = *(const bf16x8*)&As[(wm + 16 * i + ml) * 32 + kq];
#pragma unroll
    for (int j = 0; j < 4; ++j)
      fb[j] = *(const bf16x8*)&Bs[(wn + 16 * j + ml) * 32 + kq];
#pragma unroll
    for (int i = 0; i < 4; ++i)
#pragma unroll
      for (int j = 0; j < 4; ++j)
        acc[i][j] = __builtin_amdgcn_mfma_f32_16x16x32_bf16(fa[i], fb[j], acc[i][j], 0, 0, 0);
    __syncthreads();
  }

  const int rq = (lane >> 4) * 4;
#pragma unroll
  for (int j = 0; j < 4; ++j) {
    int n = n0 + wn + 16 * j + ml;
    float bv = bias[n];
#pragma unroll
    for (int i = 0; i < 4; ++i) {
#pragma unroll
      for (int r = 0; r < 4; ++r) {
        int m = m0 + wm + 16 * i + rq + r;
        if (m < MROWS) {
          int b = m / TDEC;
          int t = m - b * TDEC;
          out[((size_t)(b * 32 + t + 1)) * VOCAB + n] = acc[i][j][r] + bv;
        }
      }
    }
  }
}

extern "C" void kernel_launch(void* const* d_in, const int* in_sizes, int n_in,
                              void* d_out, int out_size, void* d_ws, size_t ws_size,
                              hipStream_t stream) {
  (void)in_sizes; (void)n_in; (void)out_size; (void)ws_size;
  const int* src      = (const int*)d_in[0];
  const int* tgt      = (const int*)d_in[1];
  const float* enc_emb = (const float*)d_in[2];
  const float* dec_emb = (const float*)d_in[3];
  const float* enc_Wih = (const float*)d_in[4];
  const float* enc_Whh = (const float*)d_in[5];
  const float* enc_bih = (const float*)d_in[6];
  const float* enc_bhh = (const float*)d_in[7];
  const float* dec_Wih = (const float*)d_in[8];
  const float* dec_Whh = (const float*)d_in[9];
  const float* dec_bih = (const float*)d_in[10];
  const float* dec_bhh = (const float*)d_in[11];
  const float* fc_W    = (const float*)d_in[12];
  const float* fc_b    = (const float*)d_in[13];
  char* ws = (char*)d_ws;
  float* hh  = (float*)(ws + OFF_HH);
  float* xpe = (float*)(ws + OFF_XPE);
  float* xpd = (float*)(ws + OFF_XPD);
  unsigned short* hs  = (unsigned short*)(ws + OFF_HS);
  unsigned short* fcw = (unsigned short*)(ws + OFF_FCW);
  unsigned* flags = (unsigned*)(ws + OFF_HS + (size_t)MROWS * HDIM * 2);
  float* out = (float*)d_out;

  hipLaunchKernelGGL(setup_k, dim3(2048), dim3(256), 0, stream, fc_W, fcw, hh, hs, out);

  XpParams xq = { src, tgt, enc_emb, dec_emb, enc_Wih, enc_bih, enc_bhh,
                  dec_Wih, dec_bih, dec_bhh, xpe, xpd };
  hipLaunchKernelGGL(xp_k, dim3(512), dim3(256), 0, stream, xq);

  RecurParams rp = { enc_Whh, dec_Whh, xpe, xpd, hh, hs, flags };
  void* args[] = { &rp };
  hipLaunchCooperativeKernel((const void*)recur_coop, dim3(NBLK), dim3(1024), args, 0, stream);

  hipLaunchKernelGGL(fc_gemm, dim3(VOCAB / 128, MPAD / 128), dim3(256), 0, stream,
                     hs, fcw, fc_b, out);
}

// Round 6
// 2228.618 us; speedup vs baseline: 1.1462x; 1.0802x over previous
//
#include <hip/hip_runtime.h>
#include <cstdint>
#include <cstddef>

// Problem dims
#define NB    64      // batch
#define SENC  64      // encoder steps
#define TDEC  31      // decoder steps (tgt[:, :-1])
#define EDIM  256
#define HDIM  512
#define VOCAB 32000
#define MROWS (NB * TDEC)   // 1984
#define MPAD  2048

// Recurrence decomposition (R6): batch-partitioned groups.
// 8 groups x 8 batches. Each group = 32 blocks computing the FULL 512-unit h
// for its 8 batches -> NO cross-group coupling -> barrier scope is 32 blocks,
// not 256. Block (gr, wid) owns units [wid*16, wid*16+16) x batches
// [gr*8, gr*8+8). 512 threads = 8 waves, wave wu owns k-slice [wu*64,+64).
#define NGRP  8
#define GBLK  32
#define NBLK  (NGRP * GBLK)  // 256

// h history: slot per global step (+1 initial). Slot layout
// hh[slot][group][512 u][8 b]. Written once (write-through to MALL), read via
// plain cached loads of cold addresses (validated R5: cold first touch must
// miss L1/L2 and fetch fresh MALL data; no fence, no invalidate).
#define HSLOT (HDIM * NB)   // 32768 floats per slot (8 grp * 512 * 8)
#define NSLOT 96            // SENC + TDEC + 1

// workspace byte offsets
#define OFF_HH   0
#define OFF_WTE  (OFF_HH + NSLOT * HSLOT * 4)
#define OFF_WTD  (OFF_WTE + 2048 * 512 * 4)
#define OFF_XPE  (OFF_WTD + 2048 * 512 * 4)
#define OFF_XPD  (OFF_XPE + 256 * SENC * 8 * NB * 4)
#define OFF_HS   (OFF_XPD + 256 * TDEC * 8 * NB * 4)
#define OFF_FCW  (OFF_HS + MPAD * HDIM * 2)
// barrier flag array (NBLK u32 = 1 KB; group gr uses [gr*32, gr*32+32))
// overlays the first bytes of the hs PAD rows (rows MROWS..MPAD-1). Those
// rows only feed fc_gemm output rows m>=MROWS, discarded by the m<MROWS
// guard — garbage is harmless.

typedef __attribute__((ext_vector_type(8))) short bf16x8;   // 8 bf16 (4 VGPRs)
typedef __attribute__((ext_vector_type(4))) float f32x4;

__device__ __forceinline__ float sigf(float x) { return 1.0f / (1.0f + __expf(-x)); }
__device__ __forceinline__ float tanhfast(float x) {
  return 1.0f - 2.0f / (__expf(2.0f * x) + 1.0f);
}
__device__ __forceinline__ unsigned short f2bf(float x) {
  unsigned int u = __float_as_uint(x);
  u += 0x7fffu + ((u >> 16) & 1u);   // RNE
  return (unsigned short)(u >> 16);
}
__device__ __forceinline__ unsigned pack2(float a, float b) {
  return (unsigned)f2bf(a) | ((unsigned)f2bf(b) << 16);
}
// force a pointer into SGPRs so dependent loads scalarize (s_load)
__device__ __forceinline__ const float* uni(const float* p) {
  uintptr_t a = (uintptr_t)p;
  unsigned lo = __builtin_amdgcn_readfirstlane((unsigned)a);
  unsigned hi = __builtin_amdgcn_readfirstlane((unsigned)(a >> 32));
  return (const float*)(((uintptr_t)hi << 32) | lo);
}

// ---------------- setup: fcw bf16 convert + W transpose/permute + zeros ----
// WTP[k][pos] layout: pos = wid*64 + gate*16 + uoff for output row
// gate*512 + wid*16 + uoff -> block (.,wid)'s 64 rows are contiguous, lane-
// coalesced per k.
__global__ __launch_bounds__(256) void setup_k(const float* __restrict__ fc_W,
                                               const float* __restrict__ eW,
                                               const float* __restrict__ dW,
                                               unsigned short* __restrict__ fcw,
                                               float* __restrict__ wte,
                                               float* __restrict__ wtd,
                                               float* __restrict__ hh,
                                               unsigned short* __restrict__ hs,
                                               float* __restrict__ out) {
  const int gt = blockIdx.x * 256 + threadIdx.x;
  const int GSZ = 2048 * 256;
  const float4* s4 = (const float4*)fc_W;
  uint4* d4 = (uint4*)fcw;
  for (int i = gt; i < (VOCAB * HDIM / 8); i += GSZ) {
    float4 x = s4[2 * i], y = s4[2 * i + 1];
    uint4 v;
    v.x = pack2(x.x, x.y); v.y = pack2(x.z, x.w);
    v.z = pack2(y.x, y.y); v.w = pack2(y.z, y.w);
    d4[i] = v;
  }
  // W transpose+permute (reads coalesced, writes scattered; one-time)
  for (int i = gt; i < 2048 * 512; i += GSZ) {
    int row = i >> 9, k = i & 511;
    int gate = row >> 9, u = row & 511;
    int pos = (u >> 4) * 64 + gate * 16 + (u & 15);
    wte[(size_t)k * 2048 + pos] = eW[i];
    wtd[(size_t)k * 2048 + pos] = dW[i];
  }
  float4 z4 = make_float4(0.f, 0.f, 0.f, 0.f);
  // out[:,0,:] = 0
  for (int j = gt; j < NB * (VOCAB / 4); j += GSZ) {
    int b = j / (VOCAB / 4), q = j - b * (VOCAB / 4);
    ((float4*)out)[(size_t)b * (32 * (VOCAB / 4)) + q] = z4;
  }
  // h_hist slot 0 = h0 = zeros
  if (gt < HSLOT / 4) ((float4*)hh)[gt] = z4;
  // hs pad rows (also zeroes the overlaid barrier flag array)
  if (gt < (MPAD - MROWS) * HDIM / 8) {
    uint4 uz = {0u, 0u, 0u, 0u};
    ((uint4*)(hs + (size_t)MROWS * HDIM))[gt] = uz;
  }
}

// ---------------- xp: input projections (unchanged layout) ----------------
// xp[s][r][b] = bias_r + sum_e Wih[row_g(r)][e] * emb[idx[b][s]][e]
__device__ void xp_phase(const int* idxmat, int istride, int S,
                         const float* emb, const float* Wih,
                         const float* bih, const float* bhh,
                         float* xp_out, int bid, int tid,
                         float* W_lds, float* pbuf, float* bias_lds) {
  const int lane = tid & 63;
  const int w = tid >> 6;
  {
    int r = tid >> 5;                  // 0..7
    int e0 = (tid & 31) * 8;           // 0..248
    int row_g = (r >> 1) * HDIM + bid * 2 + (r & 1);
    const float* sp = Wih + (size_t)row_g * EDIM + e0;
    *(float4*)&W_lds[r * EDIM + e0]     = *(const float4*)sp;
    *(float4*)&W_lds[r * EDIM + e0 + 4] = *(const float4*)(sp + 4);
    if (tid < 8) {
      int rg = (tid >> 1) * HDIM + bid * 2 + (tid & 1);
      bias_lds[tid] = bih[rg] + bhh[rg];
    }
  }
  __syncthreads();
  for (int s = 0; s < S; ++s) {
    int idx = idxmat[lane * istride + s];
    const float* xrow = emb + (size_t)idx * EDIM;
    float acc[8];
#pragma unroll
    for (int r = 0; r < 8; ++r) acc[r] = 0.0f;
    for (int e = w * 64; e < w * 64 + 64; e += 4) {
      float4 xv = *(const float4*)&xrow[e];
#pragma unroll
      for (int r = 0; r < 8; ++r) {
        float4 wv = *(const float4*)&W_lds[r * EDIM + e];
        acc[r] += wv.x * xv.x + wv.y * xv.y + wv.z * xv.z + wv.w * xv.w;
      }
    }
#pragma unroll
    for (int r = 0; r < 8; ++r) pbuf[(w * 8 + r) * 64 + lane] = acc[r];
    __syncthreads();
    if (tid < 128) {
      int unit = tid >> 6, b = tid & 63;
#pragma unroll
      for (int gate = 0; gate < 4; ++gate) {
        int r = gate * 2 + unit;
        float v = bias_lds[r];
#pragma unroll
        for (int ww = 0; ww < 4; ++ww) v += pbuf[(ww * 8 + r) * 64 + b];
        xp_out[((size_t)(bid * S + s) * 8 + r) * 64 + b] = v;
      }
    }
    __syncthreads();
  }
}

struct XpParams {
  const int* src; const int* tgt;
  const float* enc_emb; const float* dec_emb;
  const float* enc_Wih; const float* enc_bih; const float* enc_bhh;
  const float* dec_Wih; const float* dec_bih; const float* dec_bhh;
  float* xpe; float* xpd;
};

__global__ __launch_bounds__(256) void xp_k(XpParams p) {
  __shared__ __align__(16) float W_lds[8 * EDIM];
  __shared__ float pbuf[32 * 64];
  __shared__ float bias_lds[8];
  const int bid = blockIdx.x;
  if (bid < 256)
    xp_phase(p.src, SENC, SENC, p.enc_emb, p.enc_Wih, p.enc_bih, p.enc_bhh,
             p.xpe, bid, threadIdx.x, W_lds, pbuf, bias_lds);
  else
    xp_phase(p.tgt, 32, TDEC, p.dec_emb, p.dec_Wih, p.dec_bih, p.dec_bhh,
             p.xpd, bid - 256, threadIdx.x, W_lds, pbuf, bias_lds);
}

// ---------------- recurrence: 8 independent 32-block groups ----------------
// Store/flag protocol proven in R1-R5: h write-through (relaxed agent atomic
// store -> MALL); vmcnt(0)+syncthreads orders stores before the arrival
// flag; distributed per-block flags at MALL; readers' first touch of a slot
// is cold -> guaranteed fresh via the normal cached path.
// NEW: barrier scope is 32 (group-local). Groups never sync with each other.
__device__ __forceinline__ void group_barrier(unsigned* fg, int wid, unsigned gen) {
  asm volatile("s_waitcnt vmcnt(0)" ::: "memory");
  __syncthreads();
  if (threadIdx.x == 0)
    __hip_atomic_store(&fg[wid], gen, __ATOMIC_RELAXED, __HIP_MEMORY_SCOPE_AGENT);
  if (threadIdx.x < 64) {
    for (;;) {
      unsigned v = 0xffffffffu;
      if (threadIdx.x < GBLK)
        v = __hip_atomic_load(&fg[threadIdx.x], __ATOMIC_RELAXED,
                              __HIP_MEMORY_SCOPE_AGENT);
      if (__all((int)(v >= gen))) break;
      __builtin_amdgcn_s_sleep(1);
    }
  }
  __syncthreads();
}

__device__ __forceinline__ void recur_phase(const float* __restrict__ WTP,
                            const float* xp, int S, int gen0, int last_phase,
                            int gr, int wid, int tid,
                            float* pbuf, float* c_lds, float* hh,
                            unsigned short* hs_or_null, unsigned* fg) {
  const int lane = tid & 63;
  const int wu = __builtin_amdgcn_readfirstlane(tid >> 6);  // wave 0..7
  const int u0 = wid * 16;
  const int b0 = gr * 8;
  // per-lane W column pointer: lane l covers output row gate*512+u0+(l&15),
  // gate = l>>4, at k = wu*64 + j  (coalesced 256B per j)
  const float* wcol = WTP + (size_t)(wu * 64) * 2048 + wid * 64 + lane;

  const int b = tid & 7, uoff = tid >> 3;   // tail decomposition (tid<128)
  const int u = u0 + uoff;
  float xg[4];
  if (tid < 128) {
    int bid2 = u >> 1;
#pragma unroll
    for (int gate = 0; gate < 4; ++gate) {
      int r = gate * 2 + (u & 1);
      xg[gate] = xp[((size_t)(bid2 * S) * 8 + r) * 64 + (b0 + b)];
    }
  }

  for (int s = 0; s < S; ++s) {
    const int gen = gen0 + s;
    // wave-uniform h pointer -> scalar loads (s_load_dwordx8 per k), SMEM
    // pipe runs parallel to the FMA stream; cold addresses -> fresh data
    const float* hsec = uni(hh + ((size_t)gen * 8 + gr) * 4096 + wu * 512);
    float acc[8] = {0.f, 0.f, 0.f, 0.f, 0.f, 0.f, 0.f, 0.f};
#pragma unroll
    for (int j = 0; j < 64; ++j) {
      float wv = wcol[(size_t)j * 2048];
#pragma unroll
      for (int bb = 0; bb < 8; ++bb)
        acc[bb] += wv * hsec[j * 8 + bb];
    }
#pragma unroll
    for (int bb = 0; bb < 8; ++bb)
      pbuf[(wu * 8 + bb) * 64 + lane] = acc[bb];
    __syncthreads();

    float xgn[4];
    if (tid < 128) {
      float g4[4];
#pragma unroll
      for (int gate = 0; gate < 4; ++gate) {
        float v = xg[gate];
#pragma unroll
        for (int w = 0; w < 8; ++w)
          v += pbuf[(w * 8 + b) * 64 + gate * 16 + uoff];
        g4[gate] = v;
      }
      float c = c_lds[tid];
      float iv = sigf(g4[0]), fv = sigf(g4[1]);
      float gv = tanhfast(g4[2]), ov = sigf(g4[3]);
      c = fv * c + iv * gv;
      float h = ov * tanhfast(c);
      c_lds[tid] = c;
      float* hn = hh + ((size_t)(gen + 1) * 8 + gr) * 4096;
      // write-through store to MALL; drained by vmcnt(0) before the flag
      __hip_atomic_store(&hn[u0 * 8 + tid], h, __ATOMIC_RELAXED,
                         __HIP_MEMORY_SCOPE_AGENT);
      if (hs_or_null)
        hs_or_null[((size_t)(b0 + b) * TDEC + s) * HDIM + u] = f2bf(h);
      // prefetch next step's xp (cached path)
      int sn = (s + 1 < S) ? s + 1 : s;
      int bid2 = u >> 1;
#pragma unroll
      for (int gate = 0; gate < 4; ++gate) {
        int r = gate * 2 + (u & 1);
        xgn[gate] = xp[((size_t)(bid2 * S + sn) * 8 + r) * 64 + (b0 + b)];
      }
    }
    if (!(last_phase && s == S - 1))
      group_barrier(fg, wid, (unsigned)(gen + 1));
    if (tid < 128) {
#pragma unroll
      for (int gate = 0; gate < 4; ++gate) xg[gate] = xgn[gate];
    }
  }
}

struct RecurParams {
  const float* wte; const float* wtd;
  const float* xpe; const float* xpd;
  float* hh;
  unsigned short* hs;
  unsigned* flags;
};

__global__ __launch_bounds__(512, 1) void recur_coop(RecurParams p) {
  __shared__ float pbuf[64 * 64];   // 16 KB (8 waves x 8 batches x 64 rows)
  __shared__ float c_lds[128];
  const int tid = threadIdx.x;
  const int gr = blockIdx.x & 7;    // group (hopefully XCD-local; correctness
  const int wid = blockIdx.x >> 3;  // does not depend on placement)
  if (tid < 128) c_lds[tid] = 0.0f;
  __syncthreads();
  unsigned* fg = p.flags + gr * GBLK;
  recur_phase(p.wte, p.xpe, SENC, 0, 0, gr, wid, tid, pbuf, c_lds,
              p.hh, nullptr, fg);
  recur_phase(p.wtd, p.xpd, TDEC, SENC, 1, gr, wid, tid, pbuf, c_lds,
              p.hh, p.hs, fg);
}

// ---------------- FC head: logits = hs @ fcw^T + b ----------------
__global__ __launch_bounds__(256) void fc_gemm(const unsigned short* __restrict__ A,
                                               const unsigned short* __restrict__ Bm,
                                               const float* __restrict__ bias,
                                               float* __restrict__ out) {
  __shared__ __align__(16) unsigned short As[128 * 32];
  __shared__ __align__(16) unsigned short Bs[128 * 32];
  const int tid = threadIdx.x;
  const int lane = tid & 63;
  const int w = tid >> 6;
  const int m0 = blockIdx.y * 128;
  const int n0 = blockIdx.x * 128;
  const int wm = (w >> 1) * 64;
  const int wn = (w & 1) * 64;
  const int ml = lane & 15;
  const int kq = (lane >> 4) * 8;

  f32x4 acc[4][4] = {};

  for (int k0 = 0; k0 < HDIM; k0 += 32) {
    for (int c = tid; c < 512; c += 256) {
      int row = c >> 2;
      int ko = (c & 3) * 8;
      *(uint4*)&As[c * 8] = *(const uint4*)(A + (size_t)(m0 + row) * HDIM + k0 + ko);
      *(uint4*)&Bs[c * 8] = *(const uint4*)(Bm + (size_t)(n0 + row) * HDIM + k0 + ko);
    }
    __syncthreads();
    bf16x8 fa[4], fb[4];
#pragma unroll
    for (int i = 0; i < 4; ++i)
      fa[i] = *(const bf16x8*)&As[(wm + 16 * i + ml) * 32 + kq];
#pragma unroll
    for (int j = 0; j < 4; ++j)
      fb[j] = *(const bf16x8*)&Bs[(wn + 16 * j + ml) * 32 + kq];
#pragma unroll
    for (int i = 0; i < 4; ++i)
#pragma unroll
      for (int j = 0; j < 4; ++j)
        acc[i][j] = __builtin_amdgcn_mfma_f32_16x16x32_bf16(fa[i], fb[j], acc[i][j], 0, 0, 0);
    __syncthreads();
  }

  const int rq = (lane >> 4) * 4;
#pragma unroll
  for (int j = 0; j < 4; ++j) {
    int n = n0 + wn + 16 * j + ml;
    float bv = bias[n];
#pragma unroll
    for (int i = 0; i < 4; ++i) {
#pragma unroll
      for (int r = 0; r < 4; ++r) {
        int m = m0 + wm + 16 * i + rq + r;
        if (m < MROWS) {
          int b = m / TDEC;
          int t = m - b * TDEC;
          out[((size_t)(b * 32 + t + 1)) * VOCAB + n] = acc[i][j][r] + bv;
        }
      }
    }
  }
}

extern "C" void kernel_launch(void* const* d_in, const int* in_sizes, int n_in,
                              void* d_out, int out_size, void* d_ws, size_t ws_size,
                              hipStream_t stream) {
  (void)in_sizes; (void)n_in; (void)out_size; (void)ws_size;
  const int* src      = (const int*)d_in[0];
  const int* tgt      = (const int*)d_in[1];
  const float* enc_emb = (const float*)d_in[2];
  const float* dec_emb = (const float*)d_in[3];
  const float* enc_Wih = (const float*)d_in[4];
  const float* enc_Whh = (const float*)d_in[5];
  const float* enc_bih = (const float*)d_in[6];
  const float* enc_bhh = (const float*)d_in[7];
  const float* dec_Wih = (const float*)d_in[8];
  const float* dec_Whh = (const float*)d_in[9];
  const float* dec_bih = (const float*)d_in[10];
  const float* dec_bhh = (const float*)d_in[11];
  const float* fc_W    = (const float*)d_in[12];
  const float* fc_b    = (const float*)d_in[13];
  char* ws = (char*)d_ws;
  float* hh  = (float*)(ws + OFF_HH);
  float* wte = (float*)(ws + OFF_WTE);
  float* wtd = (float*)(ws + OFF_WTD);
  float* xpe = (float*)(ws + OFF_XPE);
  float* xpd = (float*)(ws + OFF_XPD);
  unsigned short* hs  = (unsigned short*)(ws + OFF_HS);
  unsigned short* fcw = (unsigned short*)(ws + OFF_FCW);
  unsigned* flags = (unsigned*)(ws + OFF_HS + (size_t)MROWS * HDIM * 2);
  float* out = (float*)d_out;

  hipLaunchKernelGGL(setup_k, dim3(2048), dim3(256), 0, stream,
                     fc_W, enc_Whh, dec_Whh, fcw, wte, wtd, hh, hs, out);

  XpParams xq = { src, tgt, enc_emb, dec_emb, enc_Wih, enc_bih, enc_bhh,
                  dec_Wih, dec_bih, dec_bhh, xpe, xpd };
  hipLaunchKernelGGL(xp_k, dim3(512), dim3(256), 0, stream, xq);

  RecurParams rp = { wte, wtd, xpe, xpd, hh, hs, flags };
  void* args[] = { &rp };
  hipLaunchCooperativeKernel((const void*)recur_coop, dim3(NBLK), dim3(512), args, 0, stream);

  hipLaunchKernelGGL(fc_gemm, dim3(VOCAB / 128, MPAD / 128), dim3(256), 0, stream,
                     hs, fcw, fc_b, out);
}